// Round 3
// baseline (2593.163 us; speedup 1.0000x reference)
//
#include <hip/hip_runtime.h>
#include <math.h>

#define HW_ 17424
#define WID 132
#define HGT 132
#define CH 256
#define MROWS 139392          // 8*17424
#define OUTOFF 35684352       // 8*256*17424

typedef __bf16 bf16x8 __attribute__((ext_vector_type(8)));
typedef float  f32x4  __attribute__((ext_vector_type(4)));
typedef unsigned short ushort_t;

// Split 8 fp32 into hi/lo bf16 (RNE; residual is exact in fp32).
__device__ __forceinline__ void split8(const float* v, bf16x8& hi, bf16x8& lo) {
#pragma unroll
    for (int e = 0; e < 8; ++e) {
        float f = v[e];
        __bf16 h = (__bf16)f;
        hi[e] = h;
        lo[e] = (__bf16)(f - (float)h);
    }
}

// ---------------------------------------------------------------------------
// Weight prep: W[K][N] fp32 -> hi/lo bf16 transposed [coloff+n][KT] (KT = dest
// K stride). Tiny; re-run every launch (re-poison safe).
// ---------------------------------------------------------------------------
__global__ __launch_bounds__(256)
void prep_w_k(const float* __restrict__ W, ushort_t* __restrict__ hi,
              ushort_t* __restrict__ lo, int K, int N, int coloff, int KT) {
    const int idx = blockIdx.x * 256 + threadIdx.x;
    if (idx >= K * N) return;
    const int n = idx / K, k = idx - n * K;
    const float f = W[(size_t)k * N + n];
    const __bf16 h = (__bf16)f;
    const __bf16 l = (__bf16)(f - (float)h);
    const size_t d = (size_t)(coloff + n) * KT + k;
    hi[d] = __builtin_bit_cast(ushort_t, h);
    lo[d] = __builtin_bit_cast(ushort_t, l);
}

// ---------------------------------------------------------------------------
// LayerNorm over channels with BCHW -> (M,256) transpose.  (unchanged)
// ---------------------------------------------------------------------------
__global__ __launch_bounds__(256)
void ln_k(const float* __restrict__ x, const float* __restrict__ w,
          const float* __restrict__ bias, float* __restrict__ out) {
    __shared__ float4 s1[256];
    __shared__ float4 s2[256];
    const int tid = threadIdx.x;              // channel
    const int b   = blockIdx.y;
    const int hw0 = blockIdx.x << 2;          // 4 positions
    const float* px = x + ((size_t)(b * CH + tid)) * HW_ + hw0;
    float4 v = *(const float4*)px;
    s1[tid] = v;
    s2[tid] = make_float4(v.x * v.x, v.y * v.y, v.z * v.z, v.w * v.w);
    __syncthreads();
    for (int off = 128; off > 0; off >>= 1) {
        if (tid < off) {
            float4 a = s1[tid], c = s1[tid + off];
            a.x += c.x; a.y += c.y; a.z += c.z; a.w += c.w;
            s1[tid] = a;
            float4 d = s2[tid], e = s2[tid + off];
            d.x += e.x; d.y += e.y; d.z += e.z; d.w += e.w;
            s2[tid] = d;
        }
        __syncthreads();
    }
    float4 sum = s1[0], sq = s2[0];
    const float wv = w[tid], bv = bias[tid];
    const float inv = 1.0f / 256.0f;
    float o[4];
    {
        float m = sum.x * inv; float var = sq.x * inv - m * m;
        o[0] = (v.x - m) * rsqrtf(var + 1e-6f) * wv + bv;
    }
    {
        float m = sum.y * inv; float var = sq.y * inv - m * m;
        o[1] = (v.y - m) * rsqrtf(var + 1e-6f) * wv + bv;
    }
    {
        float m = sum.z * inv; float var = sq.z * inv - m * m;
        o[2] = (v.z - m) * rsqrtf(var + 1e-6f) * wv + bv;
    }
    {
        float m = sum.w * inv; float var = sq.w * inv - m * m;
        o[3] = (v.w - m) * rsqrtf(var + 1e-6f) * wv + bv;
    }
    float* po = out + ((size_t)(b * HW_ + hw0)) * CH + tid;
    po[0] = o[0]; po[256] = o[1]; po[512] = o[2]; po[768] = o[3];
}

// ---------------------------------------------------------------------------
// bf16x3 split-precision MFMA GEMM with PRE-SPLIT transposed weights.
// Whi/Wlo: bf16 [N][K].  B frag = two contiguous 16B loads, no per-block split.
// EPI: 0 none, 1 exact GELU, 2 multiply by mulbuf elementwise.
// ---------------------------------------------------------------------------
template <int EPI, int KK, int NN>
__global__ __launch_bounds__(256, 2)
void mgemm_k(const float* __restrict__ A, const ushort_t* __restrict__ Whi,
             const ushort_t* __restrict__ Wlo, const float* __restrict__ bias,
             float* __restrict__ C, const float* __restrict__ mulbuf) {
    const int tid  = threadIdx.x;
    const int lane = tid & 63;
    const int wave = tid >> 6;
    const int wm = wave >> 1, wn = wave & 1;
    const int row0 = blockIdx.y * 128 + wm * 64;
    const int col0 = blockIdx.x * 128 + wn * 64;
    const int lrow = lane & 15;
    const int kg   = lane >> 4;

    const f32x4 zero = {0.f, 0.f, 0.f, 0.f};
    f32x4 acc[4][4];
#pragma unroll
    for (int i = 0; i < 4; ++i)
#pragma unroll
        for (int j = 0; j < 4; ++j) acc[i][j] = zero;

    for (int kt = 0; kt < KK; kt += 32) {
        const int kb = kt + kg * 8;
        bf16x8 ah[4], al[4], bh[4], bl[4];
#pragma unroll
        for (int nf = 0; nf < 4; ++nf) {
            const size_t wo = (size_t)(col0 + nf * 16 + lrow) * KK + kb;
            bh[nf] = *(const bf16x8*)(Whi + wo);
            bl[nf] = *(const bf16x8*)(Wlo + wo);
        }
#pragma unroll
        for (int mf = 0; mf < 4; ++mf) {
            const float* p = A + (size_t)(row0 + mf * 16 + lrow) * KK + kb;
            float buf[8];
            *(float4*)&buf[0] = *(const float4*)p;
            *(float4*)&buf[4] = *(const float4*)(p + 4);
            split8(buf, ah[mf], al[mf]);
        }
#pragma unroll
        for (int mf = 0; mf < 4; ++mf)
#pragma unroll
            for (int nf = 0; nf < 4; ++nf) {
                f32x4 c = acc[mf][nf];
                c = __builtin_amdgcn_mfma_f32_16x16x32_bf16(al[mf], bh[nf], c, 0, 0, 0);
                c = __builtin_amdgcn_mfma_f32_16x16x32_bf16(ah[mf], bl[nf], c, 0, 0, 0);
                c = __builtin_amdgcn_mfma_f32_16x16x32_bf16(ah[mf], bh[nf], c, 0, 0, 0);
                acc[mf][nf] = c;
            }
    }

    float bv[4];
#pragma unroll
    for (int nf = 0; nf < 4; ++nf) bv[nf] = bias[col0 + nf * 16 + lrow];
#pragma unroll
    for (int mf = 0; mf < 4; ++mf) {
#pragma unroll
        for (int r = 0; r < 4; ++r) {
            const int row = row0 + mf * 16 + kg * 4 + r;
#pragma unroll
            for (int nf = 0; nf < 4; ++nf) {
                const int col = col0 + nf * 16 + lrow;
                const size_t off = (size_t)row * NN + col;
                float v = acc[mf][nf][r] + bv[nf];
                if (EPI == 1) v = 0.5f * v * (1.0f + erff(v * 0.7071067811865475f));
                if (EPI == 2) v *= mulbuf[off];
                C[off] = v;
            }
        }
    }
}

// ---------------------------------------------------------------------------
// Dual-output GEMM: A (M,256) @ [q_w | ef_w] (pre-split, combined [256][256]).
// cols 0..127 -> Cq (+qb), cols 128..255 -> Ce (+efb), each (M,128).
// ---------------------------------------------------------------------------
__global__ __launch_bounds__(256, 2)
void mgemm_dual_k(const float* __restrict__ A, const ushort_t* __restrict__ Whi,
                  const ushort_t* __restrict__ Wlo, const float* __restrict__ qb,
                  const float* __restrict__ efb, float* __restrict__ Cq,
                  float* __restrict__ Ce) {
    const int tid  = threadIdx.x;
    const int lane = tid & 63;
    const int wave = tid >> 6;
    const int wm = wave >> 1, wn = wave & 1;
    const int row0 = blockIdx.y * 128 + wm * 64;
    const int col0 = blockIdx.x * 128 + wn * 64;
    const int lrow = lane & 15;
    const int kg   = lane >> 4;

    const f32x4 zero = {0.f, 0.f, 0.f, 0.f};
    f32x4 acc[4][4];
#pragma unroll
    for (int i = 0; i < 4; ++i)
#pragma unroll
        for (int j = 0; j < 4; ++j) acc[i][j] = zero;

    for (int kt = 0; kt < 256; kt += 32) {
        const int kb = kt + kg * 8;
        bf16x8 ah[4], al[4], bh[4], bl[4];
#pragma unroll
        for (int nf = 0; nf < 4; ++nf) {
            const size_t wo = (size_t)(col0 + nf * 16 + lrow) * 256 + kb;
            bh[nf] = *(const bf16x8*)(Whi + wo);
            bl[nf] = *(const bf16x8*)(Wlo + wo);
        }
#pragma unroll
        for (int mf = 0; mf < 4; ++mf) {
            const float* p = A + (size_t)(row0 + mf * 16 + lrow) * 256 + kb;
            float buf[8];
            *(float4*)&buf[0] = *(const float4*)p;
            *(float4*)&buf[4] = *(const float4*)(p + 4);
            split8(buf, ah[mf], al[mf]);
        }
#pragma unroll
        for (int mf = 0; mf < 4; ++mf)
#pragma unroll
            for (int nf = 0; nf < 4; ++nf) {
                f32x4 c = acc[mf][nf];
                c = __builtin_amdgcn_mfma_f32_16x16x32_bf16(al[mf], bh[nf], c, 0, 0, 0);
                c = __builtin_amdgcn_mfma_f32_16x16x32_bf16(ah[mf], bl[nf], c, 0, 0, 0);
                c = __builtin_amdgcn_mfma_f32_16x16x32_bf16(ah[mf], bh[nf], c, 0, 0, 0);
                acc[mf][nf] = c;
            }
    }

#pragma unroll
    for (int nf = 0; nf < 4; ++nf) {
        const int col = col0 + nf * 16 + lrow;
        const float bv = (col < 128) ? qb[col] : efb[col - 128];
        float* base = (col < 128) ? Cq : Ce;
        const int cl = col & 127;
#pragma unroll
        for (int mf = 0; mf < 4; ++mf)
#pragma unroll
            for (int r = 0; r < 4; ++r) {
                const int row = row0 + mf * 16 + kg * 4 + r;
                base[(size_t)row * 128 + cl] = acc[mf][nf][r] + bv;
            }
    }
}

// ---------------------------------------------------------------------------
// Final projection, pre-split combined weights [512][384]: cols 0..255 -> out,
// 256..511 -> out_e; output transposed to BCHW.
// ---------------------------------------------------------------------------
__global__ __launch_bounds__(256, 2)
void mgemm_proj_k(const float* __restrict__ g, const float* __restrict__ l1,
                  const float* __restrict__ l2,
                  const ushort_t* __restrict__ Whi, const ushort_t* __restrict__ Wlo,
                  const float* __restrict__ b1, const float* __restrict__ b2,
                  float* __restrict__ out) {
    const int tid  = threadIdx.x;
    const int lane = tid & 63;
    const int wave = tid >> 6;
    const int wm = wave >> 1, wn = wave & 1;
    const int row0 = blockIdx.y * 128 + wm * 64;
    const int col0 = blockIdx.x * 128 + wn * 64;   // 0..448 (gcol)
    const int half = col0 >> 8;                    // uniform per block
    const float* bsel = half ? b2 : b1;
    float* obase = out + (half ? (size_t)OUTOFF : (size_t)0);
    const int lrow = lane & 15;
    const int kg   = lane >> 4;

    const f32x4 zero = {0.f, 0.f, 0.f, 0.f};
    f32x4 acc[4][4];
#pragma unroll
    for (int i = 0; i < 4; ++i)
#pragma unroll
        for (int j = 0; j < 4; ++j) acc[i][j] = zero;

    for (int kt = 0; kt < 384; kt += 32) {
        const float* Ab = (kt < 128) ? g : (kt < 256) ? l1 : l2;
        const int kloc = (kt & 127) + kg * 8;
        const int kb = kt + kg * 8;
        bf16x8 ah[4], al[4], bh[4], bl[4];
#pragma unroll
        for (int nf = 0; nf < 4; ++nf) {
            const size_t wo = (size_t)(col0 + nf * 16 + lrow) * 384 + kb;
            bh[nf] = *(const bf16x8*)(Whi + wo);
            bl[nf] = *(const bf16x8*)(Wlo + wo);
        }
#pragma unroll
        for (int mf = 0; mf < 4; ++mf) {
            const float* p = Ab + (size_t)(row0 + mf * 16 + lrow) * 128 + kloc;
            float buf[8];
            *(float4*)&buf[0] = *(const float4*)p;
            *(float4*)&buf[4] = *(const float4*)(p + 4);
            split8(buf, ah[mf], al[mf]);
        }
#pragma unroll
        for (int mf = 0; mf < 4; ++mf)
#pragma unroll
            for (int nf = 0; nf < 4; ++nf) {
                f32x4 c = acc[mf][nf];
                c = __builtin_amdgcn_mfma_f32_16x16x32_bf16(al[mf], bh[nf], c, 0, 0, 0);
                c = __builtin_amdgcn_mfma_f32_16x16x32_bf16(ah[mf], bl[nf], c, 0, 0, 0);
                c = __builtin_amdgcn_mfma_f32_16x16x32_bf16(ah[mf], bh[nf], c, 0, 0, 0);
                acc[mf][nf] = c;
            }
    }

    float bv[4];
#pragma unroll
    for (int nf = 0; nf < 4; ++nf) bv[nf] = bsel[(col0 & 255) + nf * 16 + lrow];
#pragma unroll
    for (int mf = 0; mf < 4; ++mf) {
#pragma unroll
        for (int r = 0; r < 4; ++r) {
            const int row = row0 + mf * 16 + kg * 4 + r;
            const int bidx = row / HW_;
            const int hw = row - bidx * HW_;
#pragma unroll
            for (int nf = 0; nf < 4; ++nf) {
                const int c = (col0 & 255) + nf * 16 + lrow;
                obase[((size_t)(bidx * 256 + c)) * HW_ + hw] = acc[mf][nf][r] + bv[nf];
            }
        }
    }
}

// ---------------------------------------------------------------------------
// 22x22 blocked mean pool  (unchanged)
// ---------------------------------------------------------------------------
__global__ __launch_bounds__(256)
void pool_k(const float* __restrict__ xcl, const float* __restrict__ xel,
            float* __restrict__ pooled) {
    const int q = blockIdx.x;   // 0..35
    const int b = blockIdx.y;
    const int wi = q / 6, wj = q % 6;
    const int tid = threadIdx.x;
    const size_t base = ((size_t)(b * HW_ + wi * 22 * WID + wj * 22)) * CH + tid;
    const float* p0 = xcl + base;
    const float* p1 = xel + base;
    float s0 = 0.f, s1 = 0.f;
    for (int iy = 0; iy < 22; ++iy) {
        const size_t ro = (size_t)iy * WID * CH;
        for (int ix = 0; ix < 22; ++ix) {
            const size_t off = ro + (size_t)ix * CH;
            s0 += p0[off];
            s1 += p1[off];
        }
    }
    const float inv = 1.0f / 484.0f;
    float* dst = pooled + (size_t)(b * 36 + q) * 512;
    dst[tid] = s0 * inv;
    dst[256 + tid] = s1 * inv;
}

// ---------------------------------------------------------------------------
// m = pooled @ xe_w + xe_b  (unchanged)
// ---------------------------------------------------------------------------
__global__ __launch_bounds__(128)
void mproj_k(const float* __restrict__ pooled, const float* __restrict__ xe_w,
             const float* __restrict__ xe_b, float* __restrict__ mbuf) {
    __shared__ float p[512];
    const int q = blockIdx.x, b = blockIdx.y, tid = threadIdx.x;
    const float* prow = pooled + (size_t)(b * 36 + q) * 512;
    for (int i = tid; i < 512; i += 128) p[i] = prow[i];
    __syncthreads();
    float acc = xe_b[tid];
    for (int k = 0; k < 512; ++k) acc += p[k] * xe_w[k * 128 + tid];
    mbuf[(size_t)(b * 36 + q) * 128 + tid] = acc;
}

// ---------------------------------------------------------------------------
// Attention: 6 queries per block, kv streamed once.  (unchanged, verified)
// ---------------------------------------------------------------------------
__global__ __launch_bounds__(256)
void attn_k(const float* __restrict__ mbuf, const float* __restrict__ kv,
            float* __restrict__ aout) {
    const int qg = blockIdx.x;          // 0..5 (6 queries each)
    const int head = blockIdx.y, b = blockIdx.z;
    const int tid = threadIdx.x;
    __shared__ float ml[6][16];
    if (tid < 96) {
        const int q = tid >> 4, d = tid & 15;
        ml[q][d] = mbuf[(size_t)(b * 36 + qg * 6 + q) * 128 + head * 16 + d];
    }
    __syncthreads();

    float mx[6], sum[6], a[6][16];
#pragma unroll
    for (int q = 0; q < 6; ++q) {
        mx[q] = -INFINITY; sum[q] = 0.f;
#pragma unroll
        for (int d = 0; d < 16; ++d) a[q][d] = 0.f;
    }

    for (int j = tid; j < HW_; j += 256) {
        const float* row = kv + ((size_t)(b * HW_ + j)) * 256 + head * 16;
        float k[16], v[16];
        *(float4*)&k[0]  = *(const float4*)(row + 0);
        *(float4*)&k[4]  = *(const float4*)(row + 4);
        *(float4*)&k[8]  = *(const float4*)(row + 8);
        *(float4*)&k[12] = *(const float4*)(row + 12);
        const float* vr = row + 128;
        *(float4*)&v[0]  = *(const float4*)(vr + 0);
        *(float4*)&v[4]  = *(const float4*)(vr + 4);
        *(float4*)&v[8]  = *(const float4*)(vr + 8);
        *(float4*)&v[12] = *(const float4*)(vr + 12);
#pragma unroll
        for (int q = 0; q < 6; ++q) {
            float s = 0.f;
#pragma unroll
            for (int d = 0; d < 16; ++d) s += ml[q][d] * k[d];
            s *= 0.25f;    // d^-0.5, d=16
            const float nm = fmaxf(mx[q], s);
            const float corr = expf(mx[q] - nm);
            const float p = expf(s - nm);
            sum[q] = sum[q] * corr + p;
#pragma unroll
            for (int d = 0; d < 16; ++d) a[q][d] = a[q][d] * corr + p * v[d];
            mx[q] = nm;
        }
    }

    __shared__ float smax[256];
    __shared__ float ssum[256];
    __shared__ float sacc[256][16];
    for (int q = 0; q < 6; ++q) {
        __syncthreads();
        smax[tid] = mx[q]; ssum[tid] = sum[q];
#pragma unroll
        for (int d = 0; d < 16; ++d) sacc[tid][d] = a[q][d];
        for (int off = 128; off > 0; off >>= 1) {
            __syncthreads();
            if (tid < off) {
                const float ma = smax[tid], mb = smax[tid + off];
                const float nm = fmaxf(ma, mb);
                const float ea = expf(ma - nm), eb = expf(mb - nm);
                ssum[tid] = ssum[tid] * ea + ssum[tid + off] * eb;
                for (int d = 0; d < 16; ++d)
                    sacc[tid][d] = sacc[tid][d] * ea + sacc[tid + off][d] * eb;
                smax[tid] = nm;
            }
        }
        __syncthreads();
        if (tid < 16)
            aout[((size_t)(b * 8 + head) * 36 + qg * 6 + q) * 16 + tid] =
                sacc[0][tid] / ssum[0];
    }
}

// ---------------------------------------------------------------------------
// Bilinear upsample 6x6 -> 132x132  (unchanged)
// ---------------------------------------------------------------------------
__global__ __launch_bounds__(256)
void upsample_k(const float* __restrict__ aout, float* __restrict__ g) {
    const int tid = threadIdx.x;
    const int c = tid & 127;
    const int hw = blockIdx.x * 2 + (tid >> 7);
    const int b = blockIdx.y;
    const int h = hw / WID;
    const int w = hw - h * WID;
    const float fy = (h - 10.5f) * (1.0f / 22.0f);
    const float fx = (w - 10.5f) * (1.0f / 22.0f);
    float y0f = floorf(fy), x0f = floorf(fx);
    const float ty = fy - y0f, tx = fx - x0f;
    int y0 = (int)y0f, x0 = (int)x0f;
    int y1 = min(y0 + 1, 5), x1 = min(x0 + 1, 5);
    y0 = max(y0, 0); x0 = max(x0, 0);
    const int head = c >> 4, di = c & 15;
    const float* src = aout + ((size_t)(b * 8 + head) * 36) * 16 + di;
    const float s00 = src[(y0 * 6 + x0) * 16];
    const float s01 = src[(y0 * 6 + x1) * 16];
    const float s10 = src[(y1 * 6 + x0) * 16];
    const float s11 = src[(y1 * 6 + x1) * 16];
    const float v = (1.f - ty) * ((1.f - tx) * s00 + tx * s01)
                  + ty * ((1.f - tx) * s10 + tx * s11);
    g[((size_t)(b * HW_ + hw)) * 128 + c] = v;
}

// ---------------------------------------------------------------------------
// Depthwise 7x7 conv, sliding-window  (unchanged, verified round 2)
// ---------------------------------------------------------------------------
__global__ __launch_bounds__(256)
void dwconv_k(const float* __restrict__ in, const float* __restrict__ cw,
              const float* __restrict__ cb, float* __restrict__ out) {
    __shared__ float wl[128 * 49];
    const int tid = threadIdx.x;
    for (int i = tid; i < 128 * 49; i += 256) wl[i] = cw[i];
    __syncthreads();
    const int c  = tid & 127;
    const int xb = ((blockIdx.x << 1) + (tid >> 7)) * 22;   // 0,22,...,110
    const int h  = blockIdx.y;
    const int b  = blockIdx.z;
    const float* wc = &wl[c * 49];
    float acc[22];
    const float bias = cb[c];
#pragma unroll
    for (int i = 0; i < 22; ++i) acc[i] = bias;
    const float* ibase = in + ((size_t)b * HW_) * 128 + c;
    for (int ky = 0; ky < 7; ++ky) {
        const int y = h + ky - 3;
        if ((unsigned)y >= (unsigned)HGT) continue;
        const float* rp = ibase + (size_t)y * WID * 128;
        float v[28];
#pragma unroll
        for (int j = 0; j < 28; ++j) {
            const int x = xb - 3 + j;
            v[j] = ((unsigned)x < (unsigned)WID) ? rp[(size_t)x * 128] : 0.f;
        }
#pragma unroll
        for (int kx = 0; kx < 7; ++kx) {
            const float wv = wc[ky * 7 + kx];
#pragma unroll
            for (int i = 0; i < 22; ++i) acc[i] += v[i + kx] * wv;
        }
    }
    float* op = out + ((size_t)(b * HW_ + h * WID + xb)) * 128 + c;
#pragma unroll
    for (int i = 0; i < 22; ++i) op[(size_t)i * 128] = acc[i];
}

// ---------------------------------------------------------------------------
extern "C" void kernel_launch(void* const* d_in, const int* in_sizes, int n_in,
                              void* d_out, int out_size, void* d_ws, size_t ws_size,
                              hipStream_t stream) {
    const float* x      = (const float*)d_in[0];
    const float* x_e    = (const float*)d_in[1];
    const float* norm_w = (const float*)d_in[2];
    const float* norm_b = (const float*)d_in[3];
    const float* norme_w= (const float*)d_in[4];
    const float* norme_b= (const float*)d_in[5];
    const float* l_w    = (const float*)d_in[6];
    const float* l_b    = (const float*)d_in[7];
    const float* kv_w   = (const float*)d_in[8];
    const float* kv_b   = (const float*)d_in[9];
    const float* xe_w   = (const float*)d_in[10];
    const float* xe_b   = (const float*)d_in[11];
    const float* q_w    = (const float*)d_in[12];
    const float* q_b    = (const float*)d_in[13];
    const float* ef_w   = (const float*)d_in[14];
    const float* ef_b   = (const float*)d_in[15];
    const float* ec_w   = (const float*)d_in[16];
    const float* ec_b   = (const float*)d_in[17];
    const float* eb_w   = (const float*)d_in[18];
    const float* eb_b   = (const float*)d_in[19];
    const float* proj_w = (const float*)d_in[20];
    const float* proj_b = (const float*)d_in[21];
    const float* proje_w= (const float*)d_in[22];
    const float* proje_b= (const float*)d_in[23];
    float* out = (float*)d_out;

    float* ws = (float*)d_ws;
    const size_t MS = (size_t)MROWS * 256;
    const size_t MH = (size_t)MROWS * 128;
    float* P0 = ws;                // xcl ; later conv outputs (P0a, P0b)
    float* P1 = ws + MS;           // xel
    float* P2 = ws + 2 * MS;       // xg ; later E2 (P2a), E1 (P2b); g -> P2a
    float* P3 = ws + 3 * MS;       // kv ; later Q1/l1 (P3a), Q2/l2 (P3b)
    float* pooled = ws + 4 * MS;
    float* mbuf = pooled + 147456;
    float* aout = mbuf + 36864;
    float* P0a = P0;
    float* P0b = P0 + MH;
    float* P2a = P2;
    float* P2b = P2 + MH;
    float* P3a = P3;
    float* P3b = P3 + MH;

    // pre-split weight area (bf16 ushort), 16B-aligned
    ushort_t* wsp = (ushort_t*)(aout + 36864);
    ushort_t* Wl_hi  = wsp;                   // [256][256]
    ushort_t* Wl_lo  = Wl_hi  + 65536;
    ushort_t* Wkv_hi = Wl_lo  + 65536;        // [256][256]
    ushort_t* Wkv_lo = Wkv_hi + 65536;
    ushort_t* Wqe_hi = Wkv_lo + 65536;        // [256][256]: cols 0-127 q_w, 128-255 ef_w
    ushort_t* Wqe_lo = Wqe_hi + 65536;
    ushort_t* Web_hi = Wqe_lo + 65536;        // [128][128]
    ushort_t* Web_lo = Web_hi + 16384;
    ushort_t* Wp_hi  = Web_lo + 16384;        // [512][384]: cols 0-255 proj, 256-511 proje
    ushort_t* Wp_lo  = Wp_hi  + 196608;

    const dim3 blk(256);
    // 0. weight prep (tiny)
    prep_w_k<<<dim3(256), blk, 0, stream>>>(l_w,    Wl_hi,  Wl_lo,  256, 256, 0,   256);
    prep_w_k<<<dim3(256), blk, 0, stream>>>(kv_w,   Wkv_hi, Wkv_lo, 256, 256, 0,   256);
    prep_w_k<<<dim3(128), blk, 0, stream>>>(q_w,    Wqe_hi, Wqe_lo, 256, 128, 0,   256);
    prep_w_k<<<dim3(128), blk, 0, stream>>>(ef_w,   Wqe_hi, Wqe_lo, 256, 128, 128, 256);
    prep_w_k<<<dim3(64),  blk, 0, stream>>>(eb_w,   Web_hi, Web_lo, 128, 128, 0,   128);
    prep_w_k<<<dim3(384), blk, 0, stream>>>(proj_w, Wp_hi,  Wp_lo,  384, 256, 0,   384);
    prep_w_k<<<dim3(384), blk, 0, stream>>>(proje_w,Wp_hi,  Wp_lo,  384, 256, 256, 384);
    // 1. LayerNorms (transpose to channels-last)
    ln_k<<<dim3(HW_ / 4, 8), blk, 0, stream>>>(x, norm_w, norm_b, P0);
    ln_k<<<dim3(HW_ / 4, 8), blk, 0, stream>>>(x_e, norme_w, norme_b, P1);
    // 2. xg = gelu(xcl @ l_w + l_b)
    mgemm_k<1, 256, 256><<<dim3(2, MROWS / 128), blk, 0, stream>>>(P0, Wl_hi, Wl_lo, l_b, P2, nullptr);
    // 3. kv = xg @ kv_w + kv_b
    mgemm_k<0, 256, 256><<<dim3(2, MROWS / 128), blk, 0, stream>>>(P2, Wkv_hi, Wkv_lo, kv_b, P3, nullptr);
    // 4. pooled 6x6 of cat
    pool_k<<<dim3(36, 8), blk, 0, stream>>>(P0, P1, pooled);
    // 5. m projection
    mproj_k<<<dim3(36, 8), dim3(128), 0, stream>>>(pooled, xe_w, xe_b, mbuf);
    // 6. attention -> aout (B,8,36,16): 6 queries per block
    attn_k<<<dim3(6, 8, 8), blk, 0, stream>>>(mbuf, P3, aout);
    // 7. fused LFA gemms: dual(P0) -> q1 (P3a), ef2 (P2a); dual(P1) -> q2 (P3b), ef1 (P2b)
    mgemm_dual_k<<<dim3(2, MROWS / 128), blk, 0, stream>>>(P0, Wqe_hi, Wqe_lo, q_b, ef_b, P3a, P2a);
    mgemm_dual_k<<<dim3(2, MROWS / 128), blk, 0, stream>>>(P1, Wqe_hi, Wqe_lo, q_b, ef_b, P3b, P2b);
    // 8. depthwise convs (P0/P1 dead now): E2c -> P0a, E1c -> P0b
    dwconv_k<<<dim3(3, HGT, 8), blk, 0, stream>>>(P2a, ec_w, ec_b, P0a);
    dwconv_k<<<dim3(3, HGT, 8), blk, 0, stream>>>(P2b, ec_w, ec_b, P0b);
    // 9. eb projections with elementwise q-mul (in place): l1 -> P3a, l2 -> P3b
    mgemm_k<2, 128, 128><<<dim3(1, MROWS / 128), blk, 0, stream>>>(P0b, Web_hi, Web_lo, eb_b, P3a, P3a);
    mgemm_k<2, 128, 128><<<dim3(1, MROWS / 128), blk, 0, stream>>>(P0a, Web_hi, Web_lo, eb_b, P3b, P3b);
    // 10. g = upsample(attention out) -> P2a (E2 dead)
    upsample_k<<<dim3(HW_ / 2, 8), blk, 0, stream>>>(aout, P2a);
    // 11. fused final projection -> d_out (out, out_e)
    mgemm_proj_k<<<dim3(4, MROWS / 128), blk, 0, stream>>>(
        P2a, P3a, P3b, Wp_hi, Wp_lo, proj_b, proje_b, out);
}

// Round 4
// 2051.127 us; speedup vs baseline: 1.2643x; 1.2643x over previous
//
#include <hip/hip_runtime.h>
#include <math.h>

#define HW_ 17424
#define WID 132
#define HGT 132
#define CH 256
#define MROWS 139392          // 8*17424
#define OUTOFF 35684352       // 8*256*17424

typedef __bf16 bf16x8 __attribute__((ext_vector_type(8)));
typedef float  f32x4  __attribute__((ext_vector_type(4)));
typedef unsigned short ushort_t;

// Split 8 fp32 into hi/lo bf16 (RNE; residual is exact in fp32).
__device__ __forceinline__ void split8(const float* v, bf16x8& hi, bf16x8& lo) {
#pragma unroll
    for (int e = 0; e < 8; ++e) {
        float f = v[e];
        __bf16 h = (__bf16)f;
        hi[e] = h;
        lo[e] = (__bf16)(f - (float)h);
    }
}

// ---------------------------------------------------------------------------
// Weight prep: W[K][N] fp32 -> hi/lo bf16 in MFMA FRAGMENT ORDER:
// element (k, nd=coloff+n) -> tile = (nd/16)*(KT/32) + k/32,
// lane = ((k&31)/8)*16 + (nd&15), e = k&7; dst = tile*512 + lane*8 + e.
// A wave's fragment load is then 64 lanes x 16B CONTIGUOUS (1KB burst).
// ---------------------------------------------------------------------------
__global__ __launch_bounds__(256)
void prep_w_k(const float* __restrict__ W, ushort_t* __restrict__ hi,
              ushort_t* __restrict__ lo, int K, int N, int coloff, int KT) {
    const int idx = blockIdx.x * 256 + threadIdx.x;
    if (idx >= K * N) return;
    const int n = idx / K, k = idx - n * K;
    const float f = W[(size_t)k * N + n];
    const __bf16 h = (__bf16)f;
    const __bf16 l = (__bf16)(f - (float)h);
    const int nd = coloff + n;
    const size_t tile = (size_t)(nd >> 4) * (KT >> 5) + (k >> 5);
    const int lane = ((k & 31) >> 3) * 16 + (nd & 15);
    const size_t d = tile * 512 + (size_t)lane * 8 + (k & 7);
    hi[d] = __builtin_bit_cast(ushort_t, h);
    lo[d] = __builtin_bit_cast(ushort_t, l);
}

// ---------------------------------------------------------------------------
// LayerNorm over channels with BCHW -> (M,256) transpose.
// Thread = one channel x 16 consecutive hw (64B full-line reads).
// Channel reduction: LDS [16][257] transpose + 16-lane shfl tree.
// ---------------------------------------------------------------------------
__global__ __launch_bounds__(256)
void ln_k(const float* __restrict__ x, const float* __restrict__ w,
          const float* __restrict__ bias, float* __restrict__ out) {
    __shared__ float s1[16][257];
    __shared__ float s2[16][257];
    __shared__ float fin[16][2];
    const int tid = threadIdx.x;              // channel
    const int b   = blockIdx.y;
    const int hw0 = blockIdx.x << 4;          // 16 positions
    const float* px = x + ((size_t)(b * CH + tid)) * HW_ + hw0;
    float v[16];
    *(float4*)&v[0]  = *(const float4*)(px + 0);
    *(float4*)&v[4]  = *(const float4*)(px + 4);
    *(float4*)&v[8]  = *(const float4*)(px + 8);
    *(float4*)&v[12] = *(const float4*)(px + 12);
#pragma unroll
    for (int i = 0; i < 16; ++i) {
        s1[i][tid] = v[i];
        s2[i][tid] = v[i] * v[i];
    }
    __syncthreads();
    // group g = tid>>4 reduces hw=g over 256 channels (16 lanes strided)
    const int g = tid >> 4, j = tid & 15;
    float ps = 0.f, pq = 0.f;
#pragma unroll
    for (int m = 0; m < 16; ++m) {
        ps += s1[g][j + 16 * m];
        pq += s2[g][j + 16 * m];
    }
#pragma unroll
    for (int off = 8; off > 0; off >>= 1) {
        ps += __shfl_xor(ps, off, 16);
        pq += __shfl_xor(pq, off, 16);
    }
    if (j == 0) {
        const float m = ps * (1.0f / 256.0f);
        const float var = pq * (1.0f / 256.0f) - m * m;
        fin[g][0] = m;
        fin[g][1] = rsqrtf(var + 1e-6f);
    }
    __syncthreads();
    const float wv = w[tid], bv = bias[tid];
    float* po = out + ((size_t)(b * HW_ + hw0)) * CH + tid;
#pragma unroll
    for (int i = 0; i < 16; ++i)
        po[(size_t)i * CH] = (v[i] - fin[i][0]) * fin[i][1] * wv + bv;
}

// ---------------------------------------------------------------------------
// bf16x3 split-precision MFMA GEMM, fragment-order packed weights.
// B frag load = 1KB contiguous wave burst.  EPI: 0 none, 1 GELU, 2 mul.
// ---------------------------------------------------------------------------
template <int EPI, int KK, int NN>
__global__ __launch_bounds__(256, 2)
void mgemm_k(const float* __restrict__ A, const ushort_t* __restrict__ Whi,
             const ushort_t* __restrict__ Wlo, const float* __restrict__ bias,
             float* __restrict__ C, const float* __restrict__ mulbuf) {
    const int tid  = threadIdx.x;
    const int lane = tid & 63;
    const int wave = tid >> 6;
    const int wm = wave >> 1, wn = wave & 1;
    const int row0 = blockIdx.y * 128 + wm * 64;
    const int col0 = blockIdx.x * 128 + wn * 64;
    const int lrow = lane & 15;
    const int kg   = lane >> 4;

    const f32x4 zero = {0.f, 0.f, 0.f, 0.f};
    f32x4 acc[4][4];
#pragma unroll
    for (int i = 0; i < 4; ++i)
#pragma unroll
        for (int j = 0; j < 4; ++j) acc[i][j] = zero;

    for (int kt = 0; kt < KK; kt += 32) {
        const int kb = kt + kg * 8;
        bf16x8 ah[4], al[4], bh[4], bl[4];
#pragma unroll
        for (int nf = 0; nf < 4; ++nf) {
            const size_t wo = ((size_t)((col0 >> 4) + nf) * (KK >> 5) + (kt >> 5)) * 512
                            + (size_t)lane * 8;
            bh[nf] = *(const bf16x8*)(Whi + wo);
            bl[nf] = *(const bf16x8*)(Wlo + wo);
        }
#pragma unroll
        for (int mf = 0; mf < 4; ++mf) {
            const float* p = A + (size_t)(row0 + mf * 16 + lrow) * KK + kb;
            float buf[8];
            *(float4*)&buf[0] = *(const float4*)p;
            *(float4*)&buf[4] = *(const float4*)(p + 4);
            split8(buf, ah[mf], al[mf]);
        }
#pragma unroll
        for (int mf = 0; mf < 4; ++mf)
#pragma unroll
            for (int nf = 0; nf < 4; ++nf) {
                f32x4 c = acc[mf][nf];
                c = __builtin_amdgcn_mfma_f32_16x16x32_bf16(al[mf], bh[nf], c, 0, 0, 0);
                c = __builtin_amdgcn_mfma_f32_16x16x32_bf16(ah[mf], bl[nf], c, 0, 0, 0);
                c = __builtin_amdgcn_mfma_f32_16x16x32_bf16(ah[mf], bh[nf], c, 0, 0, 0);
                acc[mf][nf] = c;
            }
    }

    float bv[4];
#pragma unroll
    for (int nf = 0; nf < 4; ++nf) bv[nf] = bias[col0 + nf * 16 + lrow];
#pragma unroll
    for (int mf = 0; mf < 4; ++mf) {
#pragma unroll
        for (int r = 0; r < 4; ++r) {
            const int row = row0 + mf * 16 + kg * 4 + r;
#pragma unroll
            for (int nf = 0; nf < 4; ++nf) {
                const int col = col0 + nf * 16 + lrow;
                const size_t off = (size_t)row * NN + col;
                float v = acc[mf][nf][r] + bv[nf];
                if (EPI == 1) v = 0.5f * v * (1.0f + erff(v * 0.7071067811865475f));
                if (EPI == 2) v *= mulbuf[off];
                C[off] = v;
            }
        }
    }
}

// ---------------------------------------------------------------------------
// Dual-output GEMM: A (M,256) @ [q_w | ef_w] packed [256 cols][256 k].
// cols 0..127 -> Cq (+qb), cols 128..255 -> Ce (+efb), each (M,128).
// ---------------------------------------------------------------------------
__global__ __launch_bounds__(256, 2)
void mgemm_dual_k(const float* __restrict__ A, const ushort_t* __restrict__ Whi,
                  const ushort_t* __restrict__ Wlo, const float* __restrict__ qb,
                  const float* __restrict__ efb, float* __restrict__ Cq,
                  float* __restrict__ Ce) {
    const int tid  = threadIdx.x;
    const int lane = tid & 63;
    const int wave = tid >> 6;
    const int wm = wave >> 1, wn = wave & 1;
    const int row0 = blockIdx.y * 128 + wm * 64;
    const int col0 = blockIdx.x * 128 + wn * 64;
    const int lrow = lane & 15;
    const int kg   = lane >> 4;

    const f32x4 zero = {0.f, 0.f, 0.f, 0.f};
    f32x4 acc[4][4];
#pragma unroll
    for (int i = 0; i < 4; ++i)
#pragma unroll
        for (int j = 0; j < 4; ++j) acc[i][j] = zero;

    for (int kt = 0; kt < 256; kt += 32) {
        const int kb = kt + kg * 8;
        bf16x8 ah[4], al[4], bh[4], bl[4];
#pragma unroll
        for (int nf = 0; nf < 4; ++nf) {
            const size_t wo = ((size_t)((col0 >> 4) + nf) * 8 + (kt >> 5)) * 512
                            + (size_t)lane * 8;
            bh[nf] = *(const bf16x8*)(Whi + wo);
            bl[nf] = *(const bf16x8*)(Wlo + wo);
        }
#pragma unroll
        for (int mf = 0; mf < 4; ++mf) {
            const float* p = A + (size_t)(row0 + mf * 16 + lrow) * 256 + kb;
            float buf[8];
            *(float4*)&buf[0] = *(const float4*)p;
            *(float4*)&buf[4] = *(const float4*)(p + 4);
            split8(buf, ah[mf], al[mf]);
        }
#pragma unroll
        for (int mf = 0; mf < 4; ++mf)
#pragma unroll
            for (int nf = 0; nf < 4; ++nf) {
                f32x4 c = acc[mf][nf];
                c = __builtin_amdgcn_mfma_f32_16x16x32_bf16(al[mf], bh[nf], c, 0, 0, 0);
                c = __builtin_amdgcn_mfma_f32_16x16x32_bf16(ah[mf], bl[nf], c, 0, 0, 0);
                c = __builtin_amdgcn_mfma_f32_16x16x32_bf16(ah[mf], bh[nf], c, 0, 0, 0);
                acc[mf][nf] = c;
            }
    }

#pragma unroll
    for (int nf = 0; nf < 4; ++nf) {
        const int col = col0 + nf * 16 + lrow;
        const float bv = (col < 128) ? qb[col] : efb[col - 128];
        float* base = (col < 128) ? Cq : Ce;
        const int cl = col & 127;
#pragma unroll
        for (int mf = 0; mf < 4; ++mf)
#pragma unroll
            for (int r = 0; r < 4; ++r) {
                const int row = row0 + mf * 16 + kg * 4 + r;
                base[(size_t)row * 128 + cl] = acc[mf][nf][r] + bv;
            }
    }
}

// ---------------------------------------------------------------------------
// Final projection with SWAPPED MFMA operands: D' = W^T X^T (same fragments,
// transposed output ownership). Lane holds (col = cf*16+kg*4+r, hw = hf*16+lrow)
// -> 16 consecutive lanes store 16 consecutive hw = full 64B lines into BCHW.
// Packed W [512 cols][384 k]; cols 0..255 -> out, 256..511 -> out_e.
// ---------------------------------------------------------------------------
__global__ __launch_bounds__(256, 2)
void mgemm_proj_k(const float* __restrict__ g, const float* __restrict__ l1,
                  const float* __restrict__ l2,
                  const ushort_t* __restrict__ Whi, const ushort_t* __restrict__ Wlo,
                  const float* __restrict__ b1, const float* __restrict__ b2,
                  float* __restrict__ out) {
    const int tid  = threadIdx.x;
    const int lane = tid & 63;
    const int wave = tid >> 6;
    const int wm = wave >> 1, wn = wave & 1;
    const int row0 = blockIdx.y * 128 + wm * 64;
    const int col0 = blockIdx.x * 128 + wn * 64;   // 0..448
    const int half = col0 >> 8;                    // 0 -> out, 1 -> out_e
    const float* bsel = half ? b2 : b1;
    float* obase = out + (half ? (size_t)OUTOFF : (size_t)0);
    const int lrow = lane & 15;
    const int kg   = lane >> 4;

    const f32x4 zero = {0.f, 0.f, 0.f, 0.f};
    f32x4 acc[4][4];   // [cf][hf]
#pragma unroll
    for (int i = 0; i < 4; ++i)
#pragma unroll
        for (int j = 0; j < 4; ++j) acc[i][j] = zero;

    for (int kt = 0; kt < 384; kt += 32) {
        const float* Ab = (kt < 128) ? g : (kt < 256) ? l1 : l2;
        const int kloc = (kt & 127) + kg * 8;
        bf16x8 ah[4], al[4], bh[4], bl[4];
#pragma unroll
        for (int cf = 0; cf < 4; ++cf) {
            const size_t wo = ((size_t)((col0 >> 4) + cf) * 12 + (kt >> 5)) * 512
                            + (size_t)lane * 8;
            bh[cf] = *(const bf16x8*)(Whi + wo);
            bl[cf] = *(const bf16x8*)(Wlo + wo);
        }
#pragma unroll
        for (int hf = 0; hf < 4; ++hf) {
            const float* p = Ab + (size_t)(row0 + hf * 16 + lrow) * 128 + kloc;
            float buf[8];
            *(float4*)&buf[0] = *(const float4*)p;
            *(float4*)&buf[4] = *(const float4*)(p + 4);
            split8(buf, ah[hf], al[hf]);
        }
        // swapped operands: A-op = W fragment, B-op = X fragment
#pragma unroll
        for (int cf = 0; cf < 4; ++cf)
#pragma unroll
            for (int hf = 0; hf < 4; ++hf) {
                f32x4 c = acc[cf][hf];
                c = __builtin_amdgcn_mfma_f32_16x16x32_bf16(bl[cf], ah[hf], c, 0, 0, 0);
                c = __builtin_amdgcn_mfma_f32_16x16x32_bf16(bh[cf], al[hf], c, 0, 0, 0);
                c = __builtin_amdgcn_mfma_f32_16x16x32_bf16(bh[cf], ah[hf], c, 0, 0, 0);
                acc[cf][hf] = c;
            }
    }

#pragma unroll
    for (int cf = 0; cf < 4; ++cf)
#pragma unroll
        for (int r = 0; r < 4; ++r) {
            const int c = (col0 & 255) + cf * 16 + kg * 4 + r;
            const float bv = bsel[c];
#pragma unroll
            for (int hf = 0; hf < 4; ++hf) {
                const int rowb = row0 + hf * 16;
                const int bidx = rowb / HW_;
                const int hw = rowb - bidx * HW_ + lrow;
                obase[((size_t)(bidx * 256 + c)) * HW_ + hw] = acc[cf][hf][r] + bv;
            }
        }
}

// ---------------------------------------------------------------------------
// 22x22 blocked mean pool  (unchanged)
// ---------------------------------------------------------------------------
__global__ __launch_bounds__(256)
void pool_k(const float* __restrict__ xcl, const float* __restrict__ xel,
            float* __restrict__ pooled) {
    const int q = blockIdx.x;   // 0..35
    const int b = blockIdx.y;
    const int wi = q / 6, wj = q % 6;
    const int tid = threadIdx.x;
    const size_t base = ((size_t)(b * HW_ + wi * 22 * WID + wj * 22)) * CH + tid;
    const float* p0 = xcl + base;
    const float* p1 = xel + base;
    float s0 = 0.f, s1 = 0.f;
    for (int iy = 0; iy < 22; ++iy) {
        const size_t ro = (size_t)iy * WID * CH;
        for (int ix = 0; ix < 22; ++ix) {
            const size_t off = ro + (size_t)ix * CH;
            s0 += p0[off];
            s1 += p1[off];
        }
    }
    const float inv = 1.0f / 484.0f;
    float* dst = pooled + (size_t)(b * 36 + q) * 512;
    dst[tid] = s0 * inv;
    dst[256 + tid] = s1 * inv;
}

// ---------------------------------------------------------------------------
// m = pooled @ xe_w + xe_b  (unchanged)
// ---------------------------------------------------------------------------
__global__ __launch_bounds__(128)
void mproj_k(const float* __restrict__ pooled, const float* __restrict__ xe_w,
             const float* __restrict__ xe_b, float* __restrict__ mbuf) {
    __shared__ float p[512];
    const int q = blockIdx.x, b = blockIdx.y, tid = threadIdx.x;
    const float* prow = pooled + (size_t)(b * 36 + q) * 512;
    for (int i = tid; i < 512; i += 128) p[i] = prow[i];
    __syncthreads();
    float acc = xe_b[tid];
    for (int k = 0; k < 512; ++k) acc += p[k] * xe_w[k * 128 + tid];
    mbuf[(size_t)(b * 36 + q) * 128 + tid] = acc;
}

// ---------------------------------------------------------------------------
// Attention: 6 queries per block, kv streamed once.  (unchanged, verified)
// ---------------------------------------------------------------------------
__global__ __launch_bounds__(256)
void attn_k(const float* __restrict__ mbuf, const float* __restrict__ kv,
            float* __restrict__ aout) {
    const int qg = blockIdx.x;          // 0..5 (6 queries each)
    const int head = blockIdx.y, b = blockIdx.z;
    const int tid = threadIdx.x;
    __shared__ float ml[6][16];
    if (tid < 96) {
        const int q = tid >> 4, d = tid & 15;
        ml[q][d] = mbuf[(size_t)(b * 36 + qg * 6 + q) * 128 + head * 16 + d];
    }
    __syncthreads();

    float mx[6], sum[6], a[6][16];
#pragma unroll
    for (int q = 0; q < 6; ++q) {
        mx[q] = -INFINITY; sum[q] = 0.f;
#pragma unroll
        for (int d = 0; d < 16; ++d) a[q][d] = 0.f;
    }

    for (int j = tid; j < HW_; j += 256) {
        const float* row = kv + ((size_t)(b * HW_ + j)) * 256 + head * 16;
        float k[16], v[16];
        *(float4*)&k[0]  = *(const float4*)(row + 0);
        *(float4*)&k[4]  = *(const float4*)(row + 4);
        *(float4*)&k[8]  = *(const float4*)(row + 8);
        *(float4*)&k[12] = *(const float4*)(row + 12);
        const float* vr = row + 128;
        *(float4*)&v[0]  = *(const float4*)(vr + 0);
        *(float4*)&v[4]  = *(const float4*)(vr + 4);
        *(float4*)&v[8]  = *(const float4*)(vr + 8);
        *(float4*)&v[12] = *(const float4*)(vr + 12);
#pragma unroll
        for (int q = 0; q < 6; ++q) {
            float s = 0.f;
#pragma unroll
            for (int d = 0; d < 16; ++d) s += ml[q][d] * k[d];
            s *= 0.25f;    // d^-0.5, d=16
            const float nm = fmaxf(mx[q], s);
            const float corr = expf(mx[q] - nm);
            const float p = expf(s - nm);
            sum[q] = sum[q] * corr + p;
#pragma unroll
            for (int d = 0; d < 16; ++d) a[q][d] = a[q][d] * corr + p * v[d];
            mx[q] = nm;
        }
    }

    __shared__ float smax[256];
    __shared__ float ssum[256];
    __shared__ float sacc[256][16];
    for (int q = 0; q < 6; ++q) {
        __syncthreads();
        smax[tid] = mx[q]; ssum[tid] = sum[q];
#pragma unroll
        for (int d = 0; d < 16; ++d) sacc[tid][d] = a[q][d];
        for (int off = 128; off > 0; off >>= 1) {
            __syncthreads();
            if (tid < off) {
                const float ma = smax[tid], mb = smax[tid + off];
                const float nm = fmaxf(ma, mb);
                const float ea = expf(ma - nm), eb = expf(mb - nm);
                ssum[tid] = ssum[tid] * ea + ssum[tid + off] * eb;
                for (int d = 0; d < 16; ++d)
                    sacc[tid][d] = sacc[tid][d] * ea + sacc[tid + off][d] * eb;
                smax[tid] = nm;
            }
        }
        __syncthreads();
        if (tid < 16)
            aout[((size_t)(b * 8 + head) * 36 + qg * 6 + q) * 16 + tid] =
                sacc[0][tid] / ssum[0];
    }
}

// ---------------------------------------------------------------------------
// Bilinear upsample 6x6 -> 132x132  (unchanged)
// ---------------------------------------------------------------------------
__global__ __launch_bounds__(256)
void upsample_k(const float* __restrict__ aout, float* __restrict__ g) {
    const int tid = threadIdx.x;
    const int c = tid & 127;
    const int hw = blockIdx.x * 2 + (tid >> 7);
    const int b = blockIdx.y;
    const int h = hw / WID;
    const int w = hw - h * WID;
    const float fy = (h - 10.5f) * (1.0f / 22.0f);
    const float fx = (w - 10.5f) * (1.0f / 22.0f);
    float y0f = floorf(fy), x0f = floorf(fx);
    const float ty = fy - y0f, tx = fx - x0f;
    int y0 = (int)y0f, x0 = (int)x0f;
    int y1 = min(y0 + 1, 5), x1 = min(x0 + 1, 5);
    y0 = max(y0, 0); x0 = max(x0, 0);
    const int head = c >> 4, di = c & 15;
    const float* src = aout + ((size_t)(b * 8 + head) * 36) * 16 + di;
    const float s00 = src[(y0 * 6 + x0) * 16];
    const float s01 = src[(y0 * 6 + x1) * 16];
    const float s10 = src[(y1 * 6 + x0) * 16];
    const float s11 = src[(y1 * 6 + x1) * 16];
    const float v = (1.f - ty) * ((1.f - tx) * s00 + tx * s01)
                  + ty * ((1.f - tx) * s10 + tx * s11);
    g[((size_t)(b * HW_ + hw)) * 128 + c] = v;
}

// ---------------------------------------------------------------------------
// Depthwise 7x7 conv, sliding-window  (unchanged, verified round 2)
// ---------------------------------------------------------------------------
__global__ __launch_bounds__(256)
void dwconv_k(const float* __restrict__ in, const float* __restrict__ cw,
              const float* __restrict__ cb, float* __restrict__ out) {
    __shared__ float wl[128 * 49];
    const int tid = threadIdx.x;
    for (int i = tid; i < 128 * 49; i += 256) wl[i] = cw[i];
    __syncthreads();
    const int c  = tid & 127;
    const int xb = ((blockIdx.x << 1) + (tid >> 7)) * 22;   // 0,22,...,110
    const int h  = blockIdx.y;
    const int b  = blockIdx.z;
    const float* wc = &wl[c * 49];
    float acc[22];
    const float bias = cb[c];
#pragma unroll
    for (int i = 0; i < 22; ++i) acc[i] = bias;
    const float* ibase = in + ((size_t)b * HW_) * 128 + c;
    for (int ky = 0; ky < 7; ++ky) {
        const int y = h + ky - 3;
        if ((unsigned)y >= (unsigned)HGT) continue;
        const float* rp = ibase + (size_t)y * WID * 128;
        float v[28];
#pragma unroll
        for (int j = 0; j < 28; ++j) {
            const int x = xb - 3 + j;
            v[j] = ((unsigned)x < (unsigned)WID) ? rp[(size_t)x * 128] : 0.f;
        }
#pragma unroll
        for (int kx = 0; kx < 7; ++kx) {
            const float wv = wc[ky * 7 + kx];
#pragma unroll
            for (int i = 0; i < 22; ++i) acc[i] += v[i + kx] * wv;
        }
    }
    float* op = out + ((size_t)(b * HW_ + h * WID + xb)) * 128 + c;
#pragma unroll
    for (int i = 0; i < 22; ++i) op[(size_t)i * 128] = acc[i];
}

// ---------------------------------------------------------------------------
extern "C" void kernel_launch(void* const* d_in, const int* in_sizes, int n_in,
                              void* d_out, int out_size, void* d_ws, size_t ws_size,
                              hipStream_t stream) {
    const float* x      = (const float*)d_in[0];
    const float* x_e    = (const float*)d_in[1];
    const float* norm_w = (const float*)d_in[2];
    const float* norm_b = (const float*)d_in[3];
    const float* norme_w= (const float*)d_in[4];
    const float* norme_b= (const float*)d_in[5];
    const float* l_w    = (const float*)d_in[6];
    const float* l_b    = (const float*)d_in[7];
    const float* kv_w   = (const float*)d_in[8];
    const float* kv_b   = (const float*)d_in[9];
    const float* xe_w   = (const float*)d_in[10];
    const float* xe_b   = (const float*)d_in[11];
    const float* q_w    = (const float*)d_in[12];
    const float* q_b    = (const float*)d_in[13];
    const float* ef_w   = (const float*)d_in[14];
    const float* ef_b   = (const float*)d_in[15];
    const float* ec_w   = (const float*)d_in[16];
    const float* ec_b   = (const float*)d_in[17];
    const float* eb_w   = (const float*)d_in[18];
    const float* eb_b   = (const float*)d_in[19];
    const float* proj_w = (const float*)d_in[20];
    const float* proj_b = (const float*)d_in[21];
    const float* proje_w= (const float*)d_in[22];
    const float* proje_b= (const float*)d_in[23];
    float* out = (float*)d_out;

    float* ws = (float*)d_ws;
    const size_t MS = (size_t)MROWS * 256;
    const size_t MH = (size_t)MROWS * 128;
    float* P0 = ws;                // xcl ; later conv outputs (P0a, P0b)
    float* P1 = ws + MS;           // xel
    float* P2 = ws + 2 * MS;       // xg ; later E2 (P2a), E1 (P2b); g -> P2a
    float* P3 = ws + 3 * MS;       // kv ; later Q1/l1 (P3a), Q2/l2 (P3b)
    float* pooled = ws + 4 * MS;
    float* mbuf = pooled + 147456;
    float* aout = mbuf + 36864;
    float* P0a = P0;
    float* P0b = P0 + MH;
    float* P2a = P2;
    float* P2b = P2 + MH;
    float* P3a = P3;
    float* P3b = P3 + MH;

    // pre-split packed weight area (bf16 ushort), 16B-aligned
    ushort_t* wsp = (ushort_t*)(aout + 36864);
    ushort_t* Wl_hi  = wsp;                   // 256x256
    ushort_t* Wl_lo  = Wl_hi  + 65536;
    ushort_t* Wkv_hi = Wl_lo  + 65536;        // 256x256
    ushort_t* Wkv_lo = Wkv_hi + 65536;
    ushort_t* Wqe_hi = Wkv_lo + 65536;        // 256 cols x 256 k (q|ef)
    ushort_t* Wqe_lo = Wqe_hi + 65536;
    ushort_t* Web_hi = Wqe_lo + 65536;        // 128x128
    ushort_t* Web_lo = Web_hi + 16384;
    ushort_t* Wp_hi  = Web_lo + 16384;        // 512 cols x 384 k (proj|proje)
    ushort_t* Wp_lo  = Wp_hi  + 196608;

    const dim3 blk(256);
    // 0. weight prep (tiny)
    prep_w_k<<<dim3(256), blk, 0, stream>>>(l_w,    Wl_hi,  Wl_lo,  256, 256, 0,   256);
    prep_w_k<<<dim3(256), blk, 0, stream>>>(kv_w,   Wkv_hi, Wkv_lo, 256, 256, 0,   256);
    prep_w_k<<<dim3(128), blk, 0, stream>>>(q_w,    Wqe_hi, Wqe_lo, 256, 128, 0,   256);
    prep_w_k<<<dim3(128), blk, 0, stream>>>(ef_w,   Wqe_hi, Wqe_lo, 256, 128, 128, 256);
    prep_w_k<<<dim3(64),  blk, 0, stream>>>(eb_w,   Web_hi, Web_lo, 128, 128, 0,   128);
    prep_w_k<<<dim3(384), blk, 0, stream>>>(proj_w, Wp_hi,  Wp_lo,  384, 256, 0,   384);
    prep_w_k<<<dim3(384), blk, 0, stream>>>(proje_w,Wp_hi,  Wp_lo,  384, 256, 256, 384);
    // 1. LayerNorms (transpose to channels-last)
    ln_k<<<dim3(HW_ / 16, 8), blk, 0, stream>>>(x, norm_w, norm_b, P0);
    ln_k<<<dim3(HW_ / 16, 8), blk, 0, stream>>>(x_e, norme_w, norme_b, P1);
    // 2. xg = gelu(xcl @ l_w + l_b)
    mgemm_k<1, 256, 256><<<dim3(2, MROWS / 128), blk, 0, stream>>>(P0, Wl_hi, Wl_lo, l_b, P2, nullptr);
    // 3. kv = xg @ kv_w + kv_b
    mgemm_k<0, 256, 256><<<dim3(2, MROWS / 128), blk, 0, stream>>>(P2, Wkv_hi, Wkv_lo, kv_b, P3, nullptr);
    // 4. pooled 6x6 of cat
    pool_k<<<dim3(36, 8), blk, 0, stream>>>(P0, P1, pooled);
    // 5. m projection
    mproj_k<<<dim3(36, 8), dim3(128), 0, stream>>>(pooled, xe_w, xe_b, mbuf);
    // 6. attention -> aout (B,8,36,16): 6 queries per block
    attn_k<<<dim3(6, 8, 8), blk, 0, stream>>>(mbuf, P3, aout);
    // 7. fused LFA gemms: dual(P0) -> q1 (P3a), ef2 (P2a); dual(P1) -> q2 (P3b), ef1 (P2b)
    mgemm_dual_k<<<dim3(2, MROWS / 128), blk, 0, stream>>>(P0, Wqe_hi, Wqe_lo, q_b, ef_b, P3a, P2a);
    mgemm_dual_k<<<dim3(2, MROWS / 128), blk, 0, stream>>>(P1, Wqe_hi, Wqe_lo, q_b, ef_b, P3b, P2b);
    // 8. depthwise convs (P0/P1 dead now): E2c -> P0a, E1c -> P0b
    dwconv_k<<<dim3(3, HGT, 8), blk, 0, stream>>>(P2a, ec_w, ec_b, P0a);
    dwconv_k<<<dim3(3, HGT, 8), blk, 0, stream>>>(P2b, ec_w, ec_b, P0b);
    // 9. eb projections with elementwise q-mul (in place): l1 -> P3a, l2 -> P3b
    mgemm_k<2, 128, 128><<<dim3(1, MROWS / 128), blk, 0, stream>>>(P0b, Web_hi, Web_lo, eb_b, P3a, P3a);
    mgemm_k<2, 128, 128><<<dim3(1, MROWS / 128), blk, 0, stream>>>(P0a, Web_hi, Web_lo, eb_b, P3b, P3b);
    // 10. g = upsample(attention out) -> P2a (E2 dead)
    upsample_k<<<dim3(HW_ / 2, 8), blk, 0, stream>>>(aout, P2a);
    // 11. fused final projection -> d_out (out, out_e)
    mgemm_proj_k<<<dim3(4, MROWS / 128), blk, 0, stream>>>(
        P2a, P3a, P3b, Wp_hi, Wp_lo, proj_b, proje_b, out);
}